// Round 6
// baseline (535.773 us; speedup 1.0000x reference)
//
#include <hip/hip_runtime.h>
#include <hip/hip_bf16.h>
#include <cstddef>

#define NB 16
#define NQ 300
#define DM 256
#define LV_ 8400

typedef __attribute__((ext_vector_type(8))) short short8;
typedef __attribute__((ext_vector_type(4))) float f32x4;

static __device__ __forceinline__ unsigned short bf16_rne(float f) {
  unsigned int u = __builtin_bit_cast(unsigned int, f);
  u += 0x7FFFu + ((u >> 16) & 1u);
  return (unsigned short)(u >> 16);
}

static __device__ __forceinline__ unsigned int pack_bf2(float a, float b) {
  __hip_bfloat162 p = __float22bfloat162_rn(make_float2(a, b));
  unsigned int u;
  __builtin_memcpy(&u, &p, 4);
  return u;
}

// ---------------------------------------------------------------------------
// Kernel 0: coalesced transpose + bf16 round of Wv and Wout.
// dst[n][k] = bf16(src[k][n]).  grid (8,8,2), 256 threads.
// ---------------------------------------------------------------------------
__global__ __launch_bounds__(256) void prep_kernel(
    const float* __restrict__ Wv, const float* __restrict__ Wout,
    unsigned short* __restrict__ Wth, unsigned short* __restrict__ WoutT) {
  const float* src = blockIdx.z ? Wout : Wv;
  unsigned short* dst = blockIdx.z ? WoutT : Wth;
  __shared__ float tle[32][33];
  const int k0 = blockIdx.x * 32, n0 = blockIdx.y * 32;
  const int xx = threadIdx.x & 31, y4 = (threadIdx.x >> 5) * 4;
  #pragma unroll
  for (int i = 0; i < 4; ++i)
    tle[y4 + i][xx] = src[(size_t)(k0 + y4 + i) * DM + n0 + xx];
  __syncthreads();
  #pragma unroll
  for (int i = 0; i < 4; ++i)
    dst[(size_t)(n0 + y4 + i) * DM + k0 + xx] = bf16_rne(tle[xx][y4 + i]);
}

// ---------------------------------------------------------------------------
// Kernel 1: v = value @ Wv + bv, bf16 MFMA.  B-HALF RESIDENT IN LDS.
// Block = 512 threads (8 waves), grid (350, 2).  Block ny handles cols
// [ny*128,+128): that B half (128x256 bf16 = 64 KB) is staged into LDS
// ONCE (single barrier), pre-swizzled into MFMA fragment order so the hot
// loop reads are contiguous ds_read_b128 (2-way bank aliasing = free).
// After the stage there are NO barriers: each wave streams 3 consecutive
// 16-row A tiles global->pack->MFMA; the compiler is free to pipeline the
// A loads arbitrarily deep (no vmcnt(0) drain anywhere).
// ---------------------------------------------------------------------------
__global__ __launch_bounds__(512, 4) void vproj_ldsb(
    const float* __restrict__ A, const unsigned short* __restrict__ Wth,
    const float* __restrict__ bias, unsigned short* __restrict__ V) {
  // fragment f = ((c*8 + j)*4 + q4)*16 + l16  holds  B[n=j*16+l16][k=c*32+q4*8 ..+8]
  __shared__ short Bl[4096][8];   // 64 KB
  const int tid = threadIdx.x;
  const int col0 = blockIdx.y * 128;

  // ---- stage B half (coalesced global reads; one-time LDS write conflicts OK)
  const unsigned short* wsrc = Wth + (size_t)col0 * DM;
  #pragma unroll
  for (int i = 0; i < 8; ++i) {
    const int f = tid + i * 512;           // [0, 4096)
    const int n = f >> 5, m = f & 31;      // n: B row (col of Wv), m: 16B chunk
    const int c = m >> 2, q4 = m & 3, j = n >> 4, l16 = n & 15;
    const uint4 w = *(const uint4*)(wsrc + (size_t)n * DM + m * 8);
    *(uint4*)&Bl[((c * 8 + j) * 4 + q4) * 16 + l16][0] = w;
  }
  __syncthreads();   // the ONLY barrier

  const int lane = tid & 63, wave = tid >> 6;
  const int l16 = lane & 15, q4 = lane >> 4;

  for (int it = 0; it < 3; ++it) {
    const size_t row0 = ((size_t)blockIdx.x * 24 + wave * 3 + it) * 16;
    const float* ap = A + (row0 + l16) * DM + q4 * 8;

    f32x4 acc[8];
    #pragma unroll
    for (int j = 0; j < 8; ++j) acc[j] = (f32x4)0.f;

    #pragma unroll
    for (int c = 0; c < 8; ++c) {
      const float4 a0 = *(const float4*)(ap + c * 32);
      const float4 a1 = *(const float4*)(ap + c * 32 + 4);
      uint4 pk;
      pk.x = pack_bf2(a0.x, a0.y);
      pk.y = pack_bf2(a0.z, a0.w);
      pk.z = pack_bf2(a1.x, a1.y);
      pk.w = pack_bf2(a1.z, a1.w);
      const short8 afr = __builtin_bit_cast(short8, pk);
      #pragma unroll
      for (int j = 0; j < 8; ++j) {
        const short8 bfr = *(const short8*)&Bl[((c * 8 + j) * 4 + q4) * 16 + l16][0];
        acc[j] = __builtin_amdgcn_mfma_f32_16x16x32_bf16(afr, bfr, acc[j], 0, 0, 0);
      }
    }

    // C/D layout: col = lane&15 (within j-tile), row = q4*4 + r
    #pragma unroll
    for (int j = 0; j < 8; ++j) {
      const int col = col0 + j * 16 + l16;
      const float bcol = bias[col];
      #pragma unroll
      for (int r = 0; r < 4; ++r)
        V[(row0 + q4 * 4 + r) * DM + col] = bf16_rne(acc[j][r] + bcol);
    }
  }
}

// ---------------------------------------------------------------------------
// Kernel 2: fused query projections (offsets N=192 + logits N=96), fp32.
// 32x32 tile, BK=32, 256 threads, 2x2 microtile, register-prefetched.
// grid (150, 9): by<6 -> Woff tile, else -> Wattn tile.
// ---------------------------------------------------------------------------
__global__ __launch_bounds__(256) void gemm_qp(
    const float* __restrict__ q,
    const float* __restrict__ Woff, const float* __restrict__ boff,
    const float* __restrict__ Wattn, const float* __restrict__ battn,
    float* __restrict__ offb, float* __restrict__ logitb) {
  const int by = blockIdx.y;
  const float* W; const float* bias; float* C; int N, c0;
  if (by < 6) { W = Woff;  bias = boff;  C = offb;   N = 192; c0 = by * 32; }
  else        { W = Wattn; bias = battn; C = logitb; N = 96;  c0 = (by - 6) * 32; }
  const int m0 = blockIdx.x * 32;

  __shared__ float As[32][33];   // As[k][m]
  __shared__ float Bs[32][33];   // Bs[k][n]
  const int tid = threadIdx.x;
  const int ar = tid >> 3, ak = (tid & 7) * 4;
  const int kr = tid >> 3, bc = (tid & 7) * 4;
  const int tx = tid & 15, ty = tid >> 4;

  const float* apt = q + (size_t)(m0 + ar) * DM + ak;
  float4 av = *(const float4*)apt;
  float4 wv = *(const float4*)(W + (size_t)kr * N + c0 + bc);

  float acc[2][2] = {{0.f, 0.f}, {0.f, 0.f}};
  for (int kk = 0; kk < DM; kk += 32) {
    __syncthreads();
    As[ak + 0][ar] = av.x;
    As[ak + 1][ar] = av.y;
    As[ak + 2][ar] = av.z;
    As[ak + 3][ar] = av.w;
    *(float4*)&Bs[kr][bc] = wv;
    __syncthreads();
    if (kk + 32 < DM) {
      av = *(const float4*)(apt + kk + 32);
      wv = *(const float4*)(W + (size_t)(kk + 32 + kr) * N + c0 + bc);
    }
    #pragma unroll
    for (int k = 0; k < 32; ++k) {
      const float2 a2 = *(const float2*)&As[k][ty * 2];
      const float2 b2 = *(const float2*)&Bs[k][tx * 2];
      acc[0][0] = fmaf(a2.x, b2.x, acc[0][0]);
      acc[0][1] = fmaf(a2.x, b2.y, acc[0][1]);
      acc[1][0] = fmaf(a2.y, b2.x, acc[1][0]);
      acc[1][1] = fmaf(a2.y, b2.y, acc[1][1]);
    }
  }
  const float b0 = bias[c0 + tx * 2], b1 = bias[c0 + tx * 2 + 1];
  #pragma unroll
  for (int i = 0; i < 2; ++i) {
    float2 o; o.x = acc[i][0] + b0; o.y = acc[i][1] + b1;
    *(float2*)&C[(size_t)(m0 + ty * 2 + i) * N + c0 + tx * 2] = o;
  }
}

// ---------------------------------------------------------------------------
// Kernel 3: softmax + bilinear deformable sampling. ONE query per block
// (4800 blocks), XCD-locality swizzle. Gather splits the 4 corners across
// lane pairs (lane^16, same wave): 24 loads/thread, one shfl_xor reduce.
// Writes mid as bf16.
// ---------------------------------------------------------------------------
__global__ __launch_bounds__(256) void sample_kernel(
    const float* __restrict__ refp, const unsigned short* __restrict__ v,
    const float* __restrict__ off, const float* __restrict__ logits,
    unsigned short* __restrict__ mid) {
  // swizzle: XCD = blockIdx%8; each XCD serves batches {c, c+8}
  const int x = blockIdx.x;
  const int c8 = x & 7, k = x >> 3;            // k in [0,600)
  const int b = c8 + (k >= 300 ? 8 : 0);
  const int qq = (k >= 300 ? k - 300 : k);
  const int bq = b * NQ + qq;
  const int t = threadIdx.x;
  __shared__ float off_sh[192];
  __shared__ float aw_sh[96];
  __shared__ int   idx_sh[96][4];
  __shared__ float wt_sh[96][4];
  __shared__ float ref_sh[2];

  if (t < 192) off_sh[t] = off[(size_t)bq * 192 + t];
  else aw_sh[t - 192] = logits[(size_t)bq * 96 + (t - 192)];
  if (t < 32) aw_sh[64 + t] = logits[(size_t)bq * 96 + 64 + t];
  if (t < 2) ref_sh[t] = refp[bq * 4 + t];
  __syncthreads();

  if (t < 8) {
    float* aw = &aw_sh[t * 12];
    float m = -1e30f;
    #pragma unroll
    for (int i = 0; i < 12; ++i) m = fmaxf(m, aw[i]);
    float e[12], s = 0.f;
    #pragma unroll
    for (int i = 0; i < 12; ++i) { e[i] = __expf(aw[i] - m); s += e[i]; }
    const float inv = 1.f / s;
    #pragma unroll
    for (int i = 0; i < 12; ++i) aw[i] = e[i] * inv;
  }
  __syncthreads();

  if (t < 96) {
    const int r = t;
    const int h = r / 12, lp = r - h * 12;
    const int l = lp >> 2, p = lp & 3;
    const int LH[3] = {80, 40, 20};
    const int LS[3] = {0, 6400, 8000};
    const int hh = LH[l], ww = LH[l], st = LS[l];
    const int oi = ((h * 3 + l) * 4 + p) * 2;
    const float aw = aw_sh[h * 12 + lp];
    const float sx = fminf(fmaxf(ref_sh[0] + off_sh[oi], 0.f), 1.f);
    const float sy = fminf(fmaxf(ref_sh[1] + off_sh[oi + 1], 0.f), 1.f);
    const float px = sx * (float)ww - 0.5f;
    const float py = sy * (float)hh - 0.5f;
    const float x0f = floorf(px), y0f = floorf(py);
    const float fx = px - x0f, fy = py - y0f;
    const int x0 = (int)x0f, y0 = (int)y0f;
    const int x1 = x0 + 1, y1 = y0 + 1;
    const bool vx0 = (x0 >= 0) & (x0 < ww), vx1 = (x1 >= 0) & (x1 < ww);
    const bool vy0 = (y0 >= 0) & (y0 < hh), vy1 = (y1 >= 0) & (y1 < hh);
    const int x0c = min(max(x0, 0), ww - 1), x1c = min(max(x1, 0), ww - 1);
    const int y0c = min(max(y0, 0), hh - 1), y1c = min(max(y1, 0), hh - 1);
    idx_sh[r][0] = st + y0c * ww + x0c;
    idx_sh[r][1] = st + y0c * ww + x1c;
    idx_sh[r][2] = st + y1c * ww + x0c;
    idx_sh[r][3] = st + y1c * ww + x1c;
    wt_sh[r][0] = aw * (1.f - fx) * (1.f - fy) * ((vx0 & vy0) ? 1.f : 0.f);
    wt_sh[r][1] = aw * fx * (1.f - fy) * ((vx1 & vy0) ? 1.f : 0.f);
    wt_sh[r][2] = aw * (1.f - fx) * fy * ((vx0 & vy1) ? 1.f : 0.f);
    wt_sh[r][3] = aw * fx * fy * ((vx1 & vy1) ? 1.f : 0.f);
  }
  __syncthreads();

  // gather: h = t>>5, corner-half ch = (t>>4)&1 (lane^16 partner), dp = t&15
  const int h = t >> 5, ch = (t >> 4) & 1, dp = t & 15;
  const unsigned short* vb = v + (size_t)b * LV_ * DM + h * 32 + dp * 2;
  float ax = 0.f, ay = 0.f;
  #pragma unroll
  for (int r = 0; r < 12; ++r) {
    const int rr = h * 12 + r;
    #pragma unroll
    for (int cc = 0; cc < 2; ++cc) {
      const int id = idx_sh[rr][ch * 2 + cc];
      const float w = wt_sh[rr][ch * 2 + cc];
      const unsigned int u = *(const unsigned int*)(vb + (size_t)id * DM);
      ax = fmaf(w, __builtin_bit_cast(float, u << 16), ax);
      ay = fmaf(w, __builtin_bit_cast(float, u & 0xFFFF0000u), ay);
    }
  }
  ax += __shfl_xor(ax, 16, 64);
  ay += __shfl_xor(ay, 16, 64);
  if (ch == 0) {
    unsigned short* mp = mid + (size_t)bq * DM + h * 32 + dp * 2;
    *(unsigned int*)mp = pack_bf2(ax, ay);
  }
}

// ---------------------------------------------------------------------------
// Kernel 4: out = mid @ Wout + bout, bf16 MFMA, 64x64 tile, BK=32,
// register-prefetch pipelined.  grid (75, 4).
// ---------------------------------------------------------------------------
__global__ __launch_bounds__(256) void outp_mfma(
    const unsigned short* __restrict__ midb, const unsigned short* __restrict__ WoutT,
    const float* __restrict__ bias, float* __restrict__ out) {
  __shared__ short Ah[4][64][8];   // 4 KB
  __shared__ short Bh[4][64][8];   // 4 KB
  const int tid = threadIdx.x;
  const int lane = tid & 63;
  const int wave = tid >> 6;
  const int l16 = lane & 15, q4 = lane >> 4;
  const int wc = wave * 16;
  const int m0 = blockIdx.x * 64, col0 = blockIdx.y * 64;

  const int r = tid >> 2, ch = tid & 3;   // staging: row, k-chunk
  const unsigned short* apt = midb + (size_t)(m0 + r) * DM + ch * 8;
  const unsigned short* wpt = WoutT + (size_t)(col0 + r) * DM + ch * 8;
  uint4 am = *(const uint4*)apt;
  uint4 wm = *(const uint4*)wpt;

  f32x4 acc[4];
  #pragma unroll
  for (int i = 0; i < 4; ++i) acc[i] = (f32x4)0.f;

  for (int kk = 0; kk < DM; kk += 32) {
    __syncthreads();
    *(uint4*)&Ah[ch][r][0] = am;
    *(uint4*)&Bh[ch][r][0] = wm;
    __syncthreads();
    if (kk + 32 < DM) {
      am = *(const uint4*)(apt + kk + 32);
      wm = *(const uint4*)(wpt + kk + 32);
    }
    const short8 bfrag = *(const short8*)&Bh[q4][wc + l16][0];
    #pragma unroll
    for (int i = 0; i < 4; ++i) {
      const short8 af = *(const short8*)&Ah[q4][i * 16 + l16][0];
      acc[i] = __builtin_amdgcn_mfma_f32_16x16x32_bf16(af, bfrag, acc[i], 0, 0, 0);
    }
  }

  const int col = col0 + wc + l16;
  const float bcol = bias[col];
  #pragma unroll
  for (int i = 0; i < 4; ++i)
    #pragma unroll
    for (int rr = 0; rr < 4; ++rr)
      out[(size_t)(m0 + i * 16 + q4 * 4 + rr) * DM + col] = acc[i][rr] + bcol;
}

extern "C" void kernel_launch(void* const* d_in, const int* in_sizes, int n_in,
                              void* d_out, int out_size, void* d_ws, size_t ws_size,
                              hipStream_t stream) {
  (void)in_sizes; (void)n_in; (void)out_size; (void)ws_size;
  const float* query = (const float*)d_in[0];
  const float* refp  = (const float*)d_in[1];
  const float* value = (const float*)d_in[2];
  const float* Wv    = (const float*)d_in[3];
  const float* bv    = (const float*)d_in[4];
  const float* Woff  = (const float*)d_in[5];
  const float* boff  = (const float*)d_in[6];
  const float* Wattn = (const float*)d_in[7];
  const float* battn = (const float*)d_in[8];
  const float* Wout  = (const float*)d_in[9];
  const float* bout  = (const float*)d_in[10];
  float* out = (float*)d_out;

  char* ws = (char*)d_ws;
  unsigned short* v_bf  = (unsigned short*)ws;              // 68,812,800 B
  unsigned short* Wth   = (unsigned short*)(ws + 68812800); // 131,072 B
  unsigned short* WoutT = (unsigned short*)(ws + 68943872); // 131,072 B
  float* offb   = (float*)(ws + 69074944);                  // 3,686,400 B
  float* logitb = (float*)(ws + 72761344);                  // 1,843,200 B
  unsigned short* midb = (unsigned short*)(ws + 74604544);  // 2,457,600 B

  prep_kernel<<<dim3(8, 8, 2), 256, 0, stream>>>(Wv, Wout, Wth, WoutT);
  gemm_qp<<<dim3(150, 9), 256, 0, stream>>>(query, Woff, boff, Wattn, battn, offb, logitb);
  vproj_ldsb<<<dim3(350, 2), 512, 0, stream>>>(value, Wth, bv, v_bf);
  sample_kernel<<<4800, 256, 0, stream>>>(refp, v_bf, offb, logitb, midb);
  outp_mfma<<<dim3(75, 4), 256, 0, stream>>>(midb, WoutT, bout, out);
}

// Round 7
// 374.685 us; speedup vs baseline: 1.4299x; 1.4299x over previous
//
#include <hip/hip_runtime.h>
#include <hip/hip_bf16.h>
#include <cstddef>

#define NB 16
#define NQ 300
#define DM 256
#define LV_ 8400

typedef __attribute__((ext_vector_type(8))) short short8;
typedef __attribute__((ext_vector_type(4))) float f32x4;

static __device__ __forceinline__ unsigned short bf16_rne(float f) {
  unsigned int u = __builtin_bit_cast(unsigned int, f);
  u += 0x7FFFu + ((u >> 16) & 1u);
  return (unsigned short)(u >> 16);
}

static __device__ __forceinline__ unsigned int pack_bf2(float a, float b) {
  __hip_bfloat162 p = __float22bfloat162_rn(make_float2(a, b));
  unsigned int u;
  __builtin_memcpy(&u, &p, 4);
  return u;
}

// ---------------------------------------------------------------------------
// Kernel 0: coalesced transpose + bf16 round of Wv and Wout.
// dst[n][k] = bf16(src[k][n]).  grid (8,8,2), 256 threads.
// ---------------------------------------------------------------------------
__global__ __launch_bounds__(256) void prep_kernel(
    const float* __restrict__ Wv, const float* __restrict__ Wout,
    unsigned short* __restrict__ Wth, unsigned short* __restrict__ WoutT) {
  const float* src = blockIdx.z ? Wout : Wv;
  unsigned short* dst = blockIdx.z ? WoutT : Wth;
  __shared__ float tle[32][33];
  const int k0 = blockIdx.x * 32, n0 = blockIdx.y * 32;
  const int xx = threadIdx.x & 31, y4 = (threadIdx.x >> 5) * 4;
  #pragma unroll
  for (int i = 0; i < 4; ++i)
    tle[y4 + i][xx] = src[(size_t)(k0 + y4 + i) * DM + n0 + xx];
  __syncthreads();
  #pragma unroll
  for (int i = 0; i < 4; ++i)
    dst[(size_t)(n0 + y4 + i) * DM + k0 + xx] = bf16_rne(tle[xx][y4 + i]);
}

// ---------------------------------------------------------------------------
// Kernel 1: v = value @ Wv + bv, bf16 MFMA.  B-HALF RESIDENT IN LDS.
// 256 threads (4 waves), launch_bounds(256,2) -> VGPR cap 256 (NO SPILLS;
// R6's 512-thread/,4 variant capped at 128 and spilled acc to scratch:
// FETCH/WRITE showed +250 MB symmetric overage).
// Block ny stages B cols [ny*128,+128) (64 KB) into LDS once, pre-swizzled
// to MFMA fragment order (hot reads = contiguous ds_read_b128, 2-way = free).
// After the single barrier each wave grid-strides over 16-row A tiles:
// global->pack->MFMA with NO barriers, letting the compiler pipeline A loads
// deep (no vmcnt(0) drain anywhere in the loop).
// ---------------------------------------------------------------------------
__global__ __launch_bounds__(256, 2) void vproj_ldsb(
    const float* __restrict__ A, const unsigned short* __restrict__ Wth,
    const float* __restrict__ bias, unsigned short* __restrict__ V) {
  // fragment f = ((c*8 + j)*4 + q4)*16 + l16 holds B[n=j*16+l16][k=c*32+q4*8..+8]
  __shared__ short Bl[4096][8];   // 64 KB
  const int tid = threadIdx.x;
  const int col0 = blockIdx.y * 128;

  // ---- stage B half (coalesced global reads), 16 frags per thread
  const unsigned short* wsrc = Wth + (size_t)col0 * DM;
  #pragma unroll
  for (int i = 0; i < 16; ++i) {
    const int f = tid + i * 256;           // [0, 4096)
    const int n = f >> 5, m = f & 31;      // n: B row (Wv col), m: 16B chunk
    const int c = m >> 2, q4 = m & 3, j = n >> 4, l16 = n & 15;
    const uint4 w = *(const uint4*)(wsrc + (size_t)n * DM + m * 8);
    *(uint4*)&Bl[((c * 8 + j) * 4 + q4) * 16 + l16][0] = w;
  }
  __syncthreads();   // the ONLY barrier

  const int lane = tid & 63, wave = tid >> 6;
  const int l16 = lane & 15, q4 = lane >> 4;
  const int nw = gridDim.x * 4;            // total waves per column half

  for (int tile = blockIdx.x * 4 + wave; tile < 8400; tile += nw) {
    const size_t row0 = (size_t)tile * 16;
    const float* ap = A + (row0 + l16) * DM + q4 * 8;

    f32x4 acc[8];
    #pragma unroll
    for (int j = 0; j < 8; ++j) acc[j] = (f32x4)0.f;

    #pragma unroll
    for (int c = 0; c < 8; ++c) {
      const float4 a0 = *(const float4*)(ap + c * 32);
      const float4 a1 = *(const float4*)(ap + c * 32 + 4);
      uint4 pk;
      pk.x = pack_bf2(a0.x, a0.y);
      pk.y = pack_bf2(a0.z, a0.w);
      pk.z = pack_bf2(a1.x, a1.y);
      pk.w = pack_bf2(a1.z, a1.w);
      const short8 afr = __builtin_bit_cast(short8, pk);
      #pragma unroll
      for (int j = 0; j < 8; ++j) {
        const short8 bfr = *(const short8*)&Bl[((c * 8 + j) * 4 + q4) * 16 + l16][0];
        acc[j] = __builtin_amdgcn_mfma_f32_16x16x32_bf16(afr, bfr, acc[j], 0, 0, 0);
      }
    }

    // C/D layout: col = lane&15 (within j-tile), row = q4*4 + r
    #pragma unroll
    for (int j = 0; j < 8; ++j) {
      const int col = col0 + j * 16 + l16;
      const float bcol = bias[col];
      #pragma unroll
      for (int r = 0; r < 4; ++r)
        V[(row0 + q4 * 4 + r) * DM + col] = bf16_rne(acc[j][r] + bcol);
    }
  }
}

// ---------------------------------------------------------------------------
// Kernel 2: fused query projections (offsets N=192 + logits N=96), fp32.
// 32x32 tile, BK=32, 256 threads, 2x2 microtile, register-prefetched.
// grid (150, 9): by<6 -> Woff tile, else -> Wattn tile.
// ---------------------------------------------------------------------------
__global__ __launch_bounds__(256) void gemm_qp(
    const float* __restrict__ q,
    const float* __restrict__ Woff, const float* __restrict__ boff,
    const float* __restrict__ Wattn, const float* __restrict__ battn,
    float* __restrict__ offb, float* __restrict__ logitb) {
  const int by = blockIdx.y;
  const float* W; const float* bias; float* C; int N, c0;
  if (by < 6) { W = Woff;  bias = boff;  C = offb;   N = 192; c0 = by * 32; }
  else        { W = Wattn; bias = battn; C = logitb; N = 96;  c0 = (by - 6) * 32; }
  const int m0 = blockIdx.x * 32;

  __shared__ float As[32][33];   // As[k][m]
  __shared__ float Bs[32][33];   // Bs[k][n]
  const int tid = threadIdx.x;
  const int ar = tid >> 3, ak = (tid & 7) * 4;
  const int kr = tid >> 3, bc = (tid & 7) * 4;
  const int tx = tid & 15, ty = tid >> 4;

  const float* apt = q + (size_t)(m0 + ar) * DM + ak;
  float4 av = *(const float4*)apt;
  float4 wv = *(const float4*)(W + (size_t)kr * N + c0 + bc);

  float acc[2][2] = {{0.f, 0.f}, {0.f, 0.f}};
  for (int kk = 0; kk < DM; kk += 32) {
    __syncthreads();
    As[ak + 0][ar] = av.x;
    As[ak + 1][ar] = av.y;
    As[ak + 2][ar] = av.z;
    As[ak + 3][ar] = av.w;
    *(float4*)&Bs[kr][bc] = wv;
    __syncthreads();
    if (kk + 32 < DM) {
      av = *(const float4*)(apt + kk + 32);
      wv = *(const float4*)(W + (size_t)(kk + 32 + kr) * N + c0 + bc);
    }
    #pragma unroll
    for (int k = 0; k < 32; ++k) {
      const float2 a2 = *(const float2*)&As[k][ty * 2];
      const float2 b2 = *(const float2*)&Bs[k][tx * 2];
      acc[0][0] = fmaf(a2.x, b2.x, acc[0][0]);
      acc[0][1] = fmaf(a2.x, b2.y, acc[0][1]);
      acc[1][0] = fmaf(a2.y, b2.x, acc[1][0]);
      acc[1][1] = fmaf(a2.y, b2.y, acc[1][1]);
    }
  }
  const float b0 = bias[c0 + tx * 2], b1 = bias[c0 + tx * 2 + 1];
  #pragma unroll
  for (int i = 0; i < 2; ++i) {
    float2 o; o.x = acc[i][0] + b0; o.y = acc[i][1] + b1;
    *(float2*)&C[(size_t)(m0 + ty * 2 + i) * N + c0 + tx * 2] = o;
  }
}

// ---------------------------------------------------------------------------
// Kernel 3: softmax + bilinear deformable sampling. ONE query per block
// (4800 blocks), XCD-locality swizzle. Gather splits the 4 corners across
// lane pairs (lane^16, same wave): 24 loads/thread, one shfl_xor reduce.
// Writes mid as bf16.
// ---------------------------------------------------------------------------
__global__ __launch_bounds__(256) void sample_kernel(
    const float* __restrict__ refp, const unsigned short* __restrict__ v,
    const float* __restrict__ off, const float* __restrict__ logits,
    unsigned short* __restrict__ mid) {
  // swizzle: XCD = blockIdx%8; each XCD serves batches {c, c+8}
  const int x = blockIdx.x;
  const int c8 = x & 7, k = x >> 3;            // k in [0,600)
  const int b = c8 + (k >= 300 ? 8 : 0);
  const int qq = (k >= 300 ? k - 300 : k);
  const int bq = b * NQ + qq;
  const int t = threadIdx.x;
  __shared__ float off_sh[192];
  __shared__ float aw_sh[96];
  __shared__ int   idx_sh[96][4];
  __shared__ float wt_sh[96][4];
  __shared__ float ref_sh[2];

  if (t < 192) off_sh[t] = off[(size_t)bq * 192 + t];
  else aw_sh[t - 192] = logits[(size_t)bq * 96 + (t - 192)];
  if (t < 32) aw_sh[64 + t] = logits[(size_t)bq * 96 + 64 + t];
  if (t < 2) ref_sh[t] = refp[bq * 4 + t];
  __syncthreads();

  if (t < 8) {
    float* aw = &aw_sh[t * 12];
    float m = -1e30f;
    #pragma unroll
    for (int i = 0; i < 12; ++i) m = fmaxf(m, aw[i]);
    float e[12], s = 0.f;
    #pragma unroll
    for (int i = 0; i < 12; ++i) { e[i] = __expf(aw[i] - m); s += e[i]; }
    const float inv = 1.f / s;
    #pragma unroll
    for (int i = 0; i < 12; ++i) aw[i] = e[i] * inv;
  }
  __syncthreads();

  if (t < 96) {
    const int r = t;
    const int h = r / 12, lp = r - h * 12;
    const int l = lp >> 2, p = lp & 3;
    const int LH[3] = {80, 40, 20};
    const int LS[3] = {0, 6400, 8000};
    const int hh = LH[l], ww = LH[l], st = LS[l];
    const int oi = ((h * 3 + l) * 4 + p) * 2;
    const float aw = aw_sh[h * 12 + lp];
    const float sx = fminf(fmaxf(ref_sh[0] + off_sh[oi], 0.f), 1.f);
    const float sy = fminf(fmaxf(ref_sh[1] + off_sh[oi + 1], 0.f), 1.f);
    const float px = sx * (float)ww - 0.5f;
    const float py = sy * (float)hh - 0.5f;
    const float x0f = floorf(px), y0f = floorf(py);
    const float fx = px - x0f, fy = py - y0f;
    const int x0 = (int)x0f, y0 = (int)y0f;
    const int x1 = x0 + 1, y1 = y0 + 1;
    const bool vx0 = (x0 >= 0) & (x0 < ww), vx1 = (x1 >= 0) & (x1 < ww);
    const bool vy0 = (y0 >= 0) & (y0 < hh), vy1 = (y1 >= 0) & (y1 < hh);
    const int x0c = min(max(x0, 0), ww - 1), x1c = min(max(x1, 0), ww - 1);
    const int y0c = min(max(y0, 0), hh - 1), y1c = min(max(y1, 0), hh - 1);
    idx_sh[r][0] = st + y0c * ww + x0c;
    idx_sh[r][1] = st + y0c * ww + x1c;
    idx_sh[r][2] = st + y1c * ww + x0c;
    idx_sh[r][3] = st + y1c * ww + x1c;
    wt_sh[r][0] = aw * (1.f - fx) * (1.f - fy) * ((vx0 & vy0) ? 1.f : 0.f);
    wt_sh[r][1] = aw * fx * (1.f - fy) * ((vx1 & vy0) ? 1.f : 0.f);
    wt_sh[r][2] = aw * (1.f - fx) * fy * ((vx0 & vy1) ? 1.f : 0.f);
    wt_sh[r][3] = aw * fx * fy * ((vx1 & vy1) ? 1.f : 0.f);
  }
  __syncthreads();

  // gather: h = t>>5, corner-half ch = (t>>4)&1 (lane^16 partner), dp = t&15
  const int h = t >> 5, ch = (t >> 4) & 1, dp = t & 15;
  const unsigned short* vb = v + (size_t)b * LV_ * DM + h * 32 + dp * 2;
  float ax = 0.f, ay = 0.f;
  #pragma unroll
  for (int r = 0; r < 12; ++r) {
    const int rr = h * 12 + r;
    #pragma unroll
    for (int cc = 0; cc < 2; ++cc) {
      const int id = idx_sh[rr][ch * 2 + cc];
      const float w = wt_sh[rr][ch * 2 + cc];
      const unsigned int u = *(const unsigned int*)(vb + (size_t)id * DM);
      ax = fmaf(w, __builtin_bit_cast(float, u << 16), ax);
      ay = fmaf(w, __builtin_bit_cast(float, u & 0xFFFF0000u), ay);
    }
  }
  ax += __shfl_xor(ax, 16, 64);
  ay += __shfl_xor(ay, 16, 64);
  if (ch == 0) {
    unsigned short* mp = mid + (size_t)bq * DM + h * 32 + dp * 2;
    *(unsigned int*)mp = pack_bf2(ax, ay);
  }
}

// ---------------------------------------------------------------------------
// Kernel 4: out = mid @ Wout + bout, bf16 MFMA, 64x64 tile, BK=32,
// register-prefetch pipelined.  grid (75, 4).
// ---------------------------------------------------------------------------
__global__ __launch_bounds__(256) void outp_mfma(
    const unsigned short* __restrict__ midb, const unsigned short* __restrict__ WoutT,
    const float* __restrict__ bias, float* __restrict__ out) {
  __shared__ short Ah[4][64][8];   // 4 KB
  __shared__ short Bh[4][64][8];   // 4 KB
  const int tid = threadIdx.x;
  const int lane = tid & 63;
  const int wave = tid >> 6;
  const int l16 = lane & 15, q4 = lane >> 4;
  const int wc = wave * 16;
  const int m0 = blockIdx.x * 64, col0 = blockIdx.y * 64;

  const int r = tid >> 2, ch = tid & 3;   // staging: row, k-chunk
  const unsigned short* apt = midb + (size_t)(m0 + r) * DM + ch * 8;
  const unsigned short* wpt = WoutT + (size_t)(col0 + r) * DM + ch * 8;
  uint4 am = *(const uint4*)apt;
  uint4 wm = *(const uint4*)wpt;

  f32x4 acc[4];
  #pragma unroll
  for (int i = 0; i < 4; ++i) acc[i] = (f32x4)0.f;

  for (int kk = 0; kk < DM; kk += 32) {
    __syncthreads();
    *(uint4*)&Ah[ch][r][0] = am;
    *(uint4*)&Bh[ch][r][0] = wm;
    __syncthreads();
    if (kk + 32 < DM) {
      am = *(const uint4*)(apt + kk + 32);
      wm = *(const uint4*)(wpt + kk + 32);
    }
    const short8 bfrag = *(const short8*)&Bh[q4][wc + l16][0];
    #pragma unroll
    for (int i = 0; i < 4; ++i) {
      const short8 af = *(const short8*)&Ah[q4][i * 16 + l16][0];
      acc[i] = __builtin_amdgcn_mfma_f32_16x16x32_bf16(af, bfrag, acc[i], 0, 0, 0);
    }
  }

  const int col = col0 + wc + l16;
  const float bcol = bias[col];
  #pragma unroll
  for (int i = 0; i < 4; ++i)
    #pragma unroll
    for (int rr = 0; rr < 4; ++rr)
      out[(size_t)(m0 + i * 16 + q4 * 4 + rr) * DM + col] = acc[i][rr] + bcol;
}

extern "C" void kernel_launch(void* const* d_in, const int* in_sizes, int n_in,
                              void* d_out, int out_size, void* d_ws, size_t ws_size,
                              hipStream_t stream) {
  (void)in_sizes; (void)n_in; (void)out_size; (void)ws_size;
  const float* query = (const float*)d_in[0];
  const float* refp  = (const float*)d_in[1];
  const float* value = (const float*)d_in[2];
  const float* Wv    = (const float*)d_in[3];
  const float* bv    = (const float*)d_in[4];
  const float* Woff  = (const float*)d_in[5];
  const float* boff  = (const float*)d_in[6];
  const float* Wattn = (const float*)d_in[7];
  const float* battn = (const float*)d_in[8];
  const float* Wout  = (const float*)d_in[9];
  const float* bout  = (const float*)d_in[10];
  float* out = (float*)d_out;

  char* ws = (char*)d_ws;
  unsigned short* v_bf  = (unsigned short*)ws;              // 68,812,800 B
  unsigned short* Wth   = (unsigned short*)(ws + 68812800); // 131,072 B
  unsigned short* WoutT = (unsigned short*)(ws + 68943872); // 131,072 B
  float* offb   = (float*)(ws + 69074944);                  // 3,686,400 B
  float* logitb = (float*)(ws + 72761344);                  // 1,843,200 B
  unsigned short* midb = (unsigned short*)(ws + 74604544);  // 2,457,600 B

  prep_kernel<<<dim3(8, 8, 2), 256, 0, stream>>>(Wv, Wout, Wth, WoutT);
  gemm_qp<<<dim3(150, 9), 256, 0, stream>>>(query, Woff, boff, Wattn, battn, offb, logitb);
  vproj_ldsb<<<dim3(263, 2), 256, 0, stream>>>(value, Wth, bv, v_bf);
  sample_kernel<<<4800, 256, 0, stream>>>(refp, v_bf, offb, logitb, midb);
  outp_mfma<<<dim3(75, 4), 256, 0, stream>>>(midb, WoutT, bout, out);
}